// Round 4
// baseline (230.831 us; speedup 1.0000x reference)
//
#include <hip/hip_runtime.h>
#include <math.h>

// MoE gate: B=4, S=4096, H=2048, E=64, top-2, seq_aux loss.
// d_out layout (float): topk_idx [16384*2] | topk_weight [16384*2] | aux_loss [1]
//
// v5: x-stationary GEMM core, K-split across waves. Lesson from v4's counters:
//  gemm_gate was stall-bound (78us, all pipes <17%), serialized on in-loop B loads
//  (60 VGPRs, no pipelining room) + 8 barriers + LDS re-pack of x.
//  New core: A-fragment (row=lane&15, k=ks*32+(lane>>4)*8+j) is 8 contiguous floats
//  of one x row -> load DIRECTLY from global, convert once, no A-LDS, no K barriers.
//  Each wave owns K/4 (16 ks-steps) x all 64 experts (acc[4]); B load amortized
//  over 12 MFMAs. Cross-wave K-reduction via small LDS tile at the end.
//  K1 prep_b:    pack W to MFMA B-frags (bf16 hi/lo) + zero replicated aux accums.
//  K2 gemm_gate: GEMM core above + fused gate/top-3/aux + inline fp64 re-rank.
//  K3 finalize:  1 block, reduces replicated accumulators -> aux_loss.

#define TT 16384
#define HH 2048
#define EE 64
#define BB 4
#define M_TOK 16   // tokens per block
#define TAU 2e-3f  // gap threshold: >> 100x the bf16-split logit error bound
#define NREP 8     // atomic replication for aux accumulators
#define NBLK (TT / M_TOK)   // 1024

typedef float v4f __attribute__((ext_vector_type(4)));
typedef float f4v __attribute__((ext_vector_type(4)));
typedef short s8v __attribute__((ext_vector_type(8)));

__device__ __forceinline__ unsigned short f2bf(float f) {
    unsigned u = __float_as_uint(f);
    return (unsigned short)((u + 0x7fffu + ((u >> 16) & 1u)) >> 16);
}
__device__ __forceinline__ float bf2f(unsigned short h) {
    return __uint_as_float(((unsigned)h) << 16);
}

// Pre-pack W[E][H] into MFMA B-fragment order, bf16 hi/lo:
// b[nt][ks][lane][j] = w[nt*16 + (lane&15)][ks*32 + (lane>>4)*8 + j]
// Block 0 also zeroes the replicated aux accumulators (stream order covers K2).
__global__ void prep_b(const float* __restrict__ w,
                       unsigned short* __restrict__ bhi,
                       unsigned short* __restrict__ blo,
                       float* __restrict__ zreg) {
    if (blockIdx.x == 0) {
        for (int i = threadIdx.x; i < 2 * NREP * BB * EE; i += 256) zreg[i] = 0.f;
    }
    int idx = blockIdx.x * blockDim.x + threadIdx.x;   // 0..131071
    int j    = idx & 7;
    int lane = (idx >> 3) & 63;
    int ks   = (idx >> 9) & 63;
    int nt   = idx >> 15;
    int e = nt * 16 + (lane & 15);
    int k = ks * 32 + (lane >> 4) * 8 + j;
    float f = w[e * HH + k];
    unsigned short h = f2bf(f);
    bhi[idx] = h;
    blo[idx] = f2bf(f - bf2f(h));
}

// ---------------- K2: x-stationary MFMA GEMM + gate + inline rerank ----------------
__global__ __launch_bounds__(256, 4) void gemm_gate(
    const float* __restrict__ x,
    const unsigned short* __restrict__ bhi, const unsigned short* __restrict__ blo,
    const float* __restrict__ w,
    float* __restrict__ out_idx, float* __restrict__ out_w,
    float* __restrict__ g_cnt, float* __restrict__ g_ssum) {

    __shared__ float accLDS[3][16][64];            // waves 1..3 K-partials, 12 KB
    __shared__ float lg[M_TOK][68];                // logit tile, padded
    __shared__ float bssum[EE];                    // per-expert score sums
    __shared__ float bcnt[EE];                     // per-expert top-2 counts
    __shared__ int   fl[M_TOK];                    // flagged-token list (local rows)
    __shared__ int   fl_cnt;

    const int tid  = threadIdx.x;
    const int wave = tid >> 6;                  // K-quarter owner
    const int lane = tid & 63;
    const int tok0 = blockIdx.x * M_TOK;

    if (tid < EE) { bssum[tid] = 0.f; bcnt[tid] = 0.f; }
    if (tid == 0) fl_cnt = 0;

    // A: lane reads row (lane&15), k = wave*512 + ks*32 + (lane>>4)*8 + j  (contiguous 8)
    const float* __restrict__ xp =
        x + (size_t)(tok0 + (lane & 15)) * HH + wave * 512 + (lane >> 4) * 8;
    // B: shorts at ((nt*64 + wave*16 + ks)*64 + lane)*8 ; nt stride 32768, ks stride 512
    const unsigned short* __restrict__ bhp = bhi + ((size_t)(wave * 16) * 64 + lane) * 8;
    const unsigned short* __restrict__ blp = blo + ((size_t)(wave * 16) * 64 + lane) * 8;

    f4v acc[4];
#pragma unroll
    for (int nt = 0; nt < 4; ++nt) acc[nt] = f4v{0.f, 0.f, 0.f, 0.f};

#pragma unroll
    for (int ks = 0; ks < 16; ++ks) {
        v4f xa = *(const v4f*)(xp + ks * 32);
        v4f xb = *(const v4f*)(xp + ks * 32 + 4);
        s8v bhv[4], blv[4];
#pragma unroll
        for (int nt = 0; nt < 4; ++nt) {
            bhv[nt] = *(const s8v*)(bhp + (size_t)nt * 32768 + ks * 512);
            blv[nt] = *(const s8v*)(blp + (size_t)nt * 32768 + ks * 512);
        }
        // fp32 -> bf16 hi/lo split (3-term MFMA, logit err ~1e-5)
        s8v ah, al;
#pragma unroll
        for (int j = 0; j < 8; ++j) {
            float f = (j < 4) ? xa[j] : xb[j - 4];
            unsigned short h = f2bf(f);
            ah[j] = (short)h;
            al[j] = (short)f2bf(f - bf2f(h));
        }
#pragma unroll
        for (int nt = 0; nt < 4; ++nt) {
            acc[nt] = __builtin_amdgcn_mfma_f32_16x16x32_bf16(ah, bhv[nt], acc[nt], 0, 0, 0);
            acc[nt] = __builtin_amdgcn_mfma_f32_16x16x32_bf16(ah, blv[nt], acc[nt], 0, 0, 0);
            acc[nt] = __builtin_amdgcn_mfma_f32_16x16x32_bf16(al, bhv[nt], acc[nt], 0, 0, 0);
        }
    }

    // ---- cross-wave K-reduction -> lg tile ----
    // C-layout per nt: col = nt*16 + (lane&15), row = (lane>>4)*4 + r
    if (wave != 0) {
#pragma unroll
        for (int nt = 0; nt < 4; ++nt)
#pragma unroll
            for (int r = 0; r < 4; ++r)
                accLDS[wave - 1][nt * 4 + r][lane] = acc[nt][r];
    }
    __syncthreads();
    if (wave == 0) {
#pragma unroll
        for (int nt = 0; nt < 4; ++nt)
#pragma unroll
            for (int r = 0; r < 4; ++r) {
                float s = acc[nt][r] + accLDS[0][nt * 4 + r][lane]
                        + accLDS[1][nt * 4 + r][lane] + accLDS[2][nt * 4 + r][lane];
                lg[(lane >> 4) * 4 + r][nt * 16 + (lane & 15)] = s;
            }
    }
    __syncthreads();

    // ---- fused gate: each wave handles 4 tokens, lane = expert ----
    float ssum_l = 0.f;                         // per-expert softmax-score sum (4 tokens)

#pragma unroll
    for (int r = 0; r < 4; ++r) {
        const int tl = wave * 4 + r;
        const int t  = tok0 + tl;
        float l = lg[tl][lane];

        // softmax score (fp32, feeds aux only)
        float mx = l;
#pragma unroll
        for (int off = 32; off; off >>= 1) mx = fmaxf(mx, __shfl_xor(mx, off, 64));
        float p = __expf(l - mx);
        float Z = p;
#pragma unroll
        for (int off = 32; off; off >>= 1) Z += __shfl_xor(Z, off, 64);
        ssum_l += p / Z;

        // top-3 by fp32 logit (tie -> lower index); cl[2] only feeds the flag
        float v = l;
        int cand[3]; float cl[3];
#pragma unroll
        for (int q = 0; q < 3; ++q) {
            float bv = v; int bi = lane;
#pragma unroll
            for (int off = 32; off; off >>= 1) {
                float ov = __shfl_xor(bv, off, 64);
                int   oi = __shfl_xor(bi, off, 64);
                if (ov > bv || (ov == bv && oi < bi)) { bv = ov; bi = oi; }
            }
            cand[q] = bi; cl[q] = bv;
            if (lane == bi) v = -3.4e38f;
        }

        if (lane == 0) {
            atomicAdd(&bcnt[cand[0]], 1.f);      // LDS atomics, trivial
            atomicAdd(&bcnt[cand[1]], 1.f);
            float w1 = 1.f / (1.f + __expf(cl[1] - cl[0]));  // softmax denom cancels
            out_idx[t * 2]     = (float)cand[0];
            out_idx[t * 2 + 1] = (float)cand[1];
            out_w[t * 2]       = w1;
            out_w[t * 2 + 1]   = 1.f - w1;
            if (cl[0] - cl[1] < TAU || cl[1] - cl[2] < TAU) {
                int pos = atomicAdd(&fl_cnt, 1);
                fl[pos] = tl;
            }
        }
    }

    atomicAdd(&bssum[lane], ssum_l);            // 4 waves -> LDS
    __syncthreads();                            // bcnt/bssum/fl complete

    // ---- publish per-block partials: ONE relaxed atomicAdd per expert ----
    {
        const int b   = tok0 >> 12;             // block-uniform batch index
        const int rep = (blockIdx.x & (NREP - 1)) * (BB * EE);
        if (tid < EE)
            atomicAdd(&g_cnt[rep + b * EE + tid], bcnt[tid]);
        else if (tid < 2 * EE)
            atomicAdd(&g_ssum[rep + b * EE + (tid - EE)], bssum[tid - EE]);
    }

    // ---- inline fp64 exact re-rank of this block's flagged tokens (~0.5/block) ----
    const int nfl = fl_cnt;
    for (int i = wave; i < nfl; i += 4) {
        const int tl = fl[i];
        const int t  = tok0 + tl;
        float l = lg[tl][lane];

        float v = l;
        int cand4[4];
#pragma unroll
        for (int q = 0; q < 4; ++q) {
            float bv = v; int bi = lane;
#pragma unroll
            for (int off = 32; off; off >>= 1) {
                float ov = __shfl_xor(bv, off, 64);
                int   oi = __shfl_xor(bi, off, 64);
                if (ov > bv || (ov == bv && oi < bi)) { bv = ov; bi = oi; }
            }
            cand4[q] = bi;
            if (lane == bi) v = -3.4e38f;
        }

        const float* __restrict__ xt  = x + (size_t)t * HH;          // L2-hot
        const float* __restrict__ w0p = w + (size_t)cand4[0] * HH;
        const float* __restrict__ w1p = w + (size_t)cand4[1] * HH;
        const float* __restrict__ w2p = w + (size_t)cand4[2] * HH;
        const float* __restrict__ w3p = w + (size_t)cand4[3] * HH;
        double d0 = 0.0, d1 = 0.0, d2 = 0.0, d3 = 0.0;
#pragma unroll
        for (int ii = 0; ii < 8; ++ii) {
            const int k = ii * 256 + lane * 4;
            v4f xv = *(const v4f*)(xt + k);
            v4f a0 = *(const v4f*)(w0p + k);
            v4f a1 = *(const v4f*)(w1p + k);
            v4f a2 = *(const v4f*)(w2p + k);
            v4f a3 = *(const v4f*)(w3p + k);
            double dx0 = (double)xv.x, dx1 = (double)xv.y;
            double dx2 = (double)xv.z, dx3 = (double)xv.w;
            d0 = fma(dx0, (double)a0.x, d0); d0 = fma(dx1, (double)a0.y, d0);
            d0 = fma(dx2, (double)a0.z, d0); d0 = fma(dx3, (double)a0.w, d0);
            d1 = fma(dx0, (double)a1.x, d1); d1 = fma(dx1, (double)a1.y, d1);
            d1 = fma(dx2, (double)a1.z, d1); d1 = fma(dx3, (double)a1.w, d1);
            d2 = fma(dx0, (double)a2.x, d2); d2 = fma(dx1, (double)a2.y, d2);
            d2 = fma(dx2, (double)a2.z, d2); d2 = fma(dx3, (double)a2.w, d2);
            d3 = fma(dx0, (double)a3.x, d3); d3 = fma(dx1, (double)a3.y, d3);
            d3 = fma(dx2, (double)a3.z, d3); d3 = fma(dx3, (double)a3.w, d3);
        }
#pragma unroll
        for (int off = 32; off; off >>= 1) {
            d0 += __shfl_xor(d0, off, 64);
            d1 += __shfl_xor(d1, off, 64);
            d2 += __shfl_xor(d2, off, 64);
            d3 += __shfl_xor(d3, off, 64);
        }

        double bd[4] = {d0, d1, d2, d3};
        int e1 = cand4[0]; double l1 = bd[0];
#pragma unroll
        for (int q = 1; q < 4; ++q)
            if (bd[q] > l1 || (bd[q] == l1 && cand4[q] < e1)) { l1 = bd[q]; e1 = cand4[q]; }
        int e2 = -1; double l2 = -1e300;
#pragma unroll
        for (int q = 0; q < 4; ++q) {
            if (cand4[q] == e1) continue;
            if (e2 < 0 || bd[q] > l2 || (bd[q] == l2 && cand4[q] < e2)) { l2 = bd[q]; e2 = cand4[q]; }
        }

        double w1d = 1.0 / (1.0 + exp(l2 - l1));
        if (lane == 0) {
            out_idx[t * 2]     = (float)e1;
            out_idx[t * 2 + 1] = (float)e2;
            out_w[t * 2]       = (float)w1d;
            out_w[t * 2 + 1]   = (float)(1.0 - w1d);
        }
    }
}

// aux = 0.01/(B * 128 * S) * sum_{b,e} cnt[b,e]*ssum[b,e]   (E/(S*K)=1/128)
__global__ void finalize(const float* __restrict__ g_cnt,
                         const float* __restrict__ g_ssum,
                         float* __restrict__ aux_out) {
    int lane = threadIdx.x;  // 64 threads, lane = expert
    float a = 0.f;
    for (int b = 0; b < BB; ++b) {
        float c = 0.f, ss = 0.f;
#pragma unroll
        for (int r = 0; r < NREP; ++r) {
            c  += g_cnt[r * (BB * EE) + b * EE + lane];
            ss += g_ssum[r * (BB * EE) + b * EE + lane];
        }
        a += c * ss;
    }
#pragma unroll
    for (int off = 32; off; off >>= 1) a += __shfl_xor(a, off, 64);
    if (lane == 0) aux_out[0] = a * (0.01f / (4.f * 128.f * 4096.f));
}

extern "C" void kernel_launch(void* const* d_in, const int* in_sizes, int n_in,
                              void* d_out, int out_size, void* d_ws, size_t ws_size,
                              hipStream_t stream) {
    const float* x = (const float*)d_in[0];   // [4,4096,2048]
    const float* w = (const float*)d_in[1];   // [64,2048]
    float* out = (float*)d_out;
    float* out_idx = out;                 // [16384*2]
    float* out_w   = out + 2 * TT;        // [16384*2]
    float* aux     = out + 4 * TT;        // [1]

    // ws layout
    unsigned short* bhi = (unsigned short*)d_ws;                    // 256 KB
    unsigned short* blo = bhi + (size_t)EE * HH;                    // 256 KB
    float* g_cnt  = (float*)(blo + (size_t)EE * HH);                // 8 KB
    float* g_ssum = g_cnt + NREP * BB * EE;                         // 8 KB

    prep_b<<<(EE * HH) / 256, 256, 0, stream>>>(w, bhi, blo, g_cnt);
    gemm_gate<<<NBLK, 256, 0, stream>>>(x, bhi, blo, w, out_idx, out_w,
                                        g_cnt, g_ssum);
    finalize<<<1, 64, 0, stream>>>(g_cnt, g_ssum, aux);
}

// Round 5
// 223.492 us; speedup vs baseline: 1.0328x; 1.0328x over previous
//
#include <hip/hip_runtime.h>
#include <math.h>

// MoE gate: B=4, S=4096, H=2048, E=64, top-2, seq_aux loss.
// d_out layout (float): topk_idx [16384*2] | topk_weight [16384*2] | aux_loss [1]
//
// v6: attack the latency-stall gemm (v5: 89us, VGPR=56 -> no load pipelining,
//     occupancy grid-capped, 512 MB B re-reads).
//  - M_TOK=32, 512 threads, 8 waves = 4 K-quarters x 2 expert-halves: each wave
//    reads a DISJOINT 64 KB of B -> B traffic halves to 256 MB, B loads amortize
//    over 12 MFMAs; grid 512 -> 2 blocks/CU x 8 waves = 16 waves/CU sustained.
//  - Explicit register double-buffer (ping-pong, compile-time indexed): next-ks
//    A+B loads issued BEFORE current-ks convert+MFMA -> counted vmcnt waits
//    instead of per-ks vmcnt(0) serialization. launch_bounds(512,4) = 128 VGPRs.
//  - Cross-wave K-reduction via LDS, then the proven fused gate / inline fp64
//    re-rank / replicated-atomic aux path (v4's, stride-adjusted to 8 waves).
//  K1 prep_b:    pack W to MFMA B-frags (bf16 hi/lo) + zero replicated aux accums.
//  K2 gemm_gate: core above + fused gate/top-3/aux + inline fp64 re-rank.
//  K3 finalize:  1 block, reduces replicated accumulators -> aux_loss.

#define TT 16384
#define HH 2048
#define EE 64
#define BB 4
#define M_TOK 32   // tokens per block
#define TAU 2e-3f  // gap threshold: >> 100x the bf16-split logit error bound
#define NREP 8     // atomic replication for aux accumulators
#define NBLK (TT / M_TOK)   // 512

typedef float v4f __attribute__((ext_vector_type(4)));
typedef float f4v __attribute__((ext_vector_type(4)));
typedef short s8v __attribute__((ext_vector_type(8)));

__device__ __forceinline__ unsigned short f2bf(float f) {
    unsigned u = __float_as_uint(f);
    return (unsigned short)((u + 0x7fffu + ((u >> 16) & 1u)) >> 16);
}
__device__ __forceinline__ float bf2f(unsigned short h) {
    return __uint_as_float(((unsigned)h) << 16);
}

// Pre-pack W[E][H] into MFMA B-fragment order, bf16 hi/lo:
// b[nt][ks64][lane][j] = w[nt*16 + (lane&15)][ks64*32 + (lane>>4)*8 + j]
// Block 0 also zeroes the replicated aux accumulators (stream order covers K2).
__global__ void prep_b(const float* __restrict__ w,
                       unsigned short* __restrict__ bhi,
                       unsigned short* __restrict__ blo,
                       float* __restrict__ zreg) {
    if (blockIdx.x == 0) {
        for (int i = threadIdx.x; i < 2 * NREP * BB * EE; i += 256) zreg[i] = 0.f;
    }
    int idx = blockIdx.x * blockDim.x + threadIdx.x;   // 0..131071
    int j    = idx & 7;
    int lane = (idx >> 3) & 63;
    int ks   = (idx >> 9) & 63;
    int nt   = idx >> 15;
    int e = nt * 16 + (lane & 15);
    int k = ks * 32 + (lane >> 4) * 8 + j;
    float f = w[e * HH + k];
    unsigned short h = f2bf(f);
    bhi[idx] = h;
    blo[idx] = f2bf(f - bf2f(h));
}

// ---------------- K2: pipelined x-stationary MFMA GEMM + gate + inline rerank ----------------
__global__ __launch_bounds__(512, 4) void gemm_gate(
    const float* __restrict__ x,
    const unsigned short* __restrict__ bhi, const unsigned short* __restrict__ blo,
    const float* __restrict__ w,
    float* __restrict__ out_idx, float* __restrict__ out_w,
    float* __restrict__ g_cnt, float* __restrict__ g_ssum) {

    __shared__ float accLDS[3][M_TOK][64];         // kq 1..3 partials, 24 KB
    __shared__ float lg[M_TOK][68];                // logit tile, padded
    __shared__ float bssum[EE];                    // per-expert score sums
    __shared__ float bcnt[EE];                     // per-expert top-2 counts
    __shared__ int   fl[M_TOK];                    // flagged-token list (local rows)
    __shared__ int   fl_cnt;

    const int tid   = threadIdx.x;
    const int wavei = tid >> 6;                 // 0..7
    const int lane  = tid & 63;
    const int kq    = wavei >> 1;               // K-quarter (512 floats)
    const int nth   = wavei & 1;                // expert half (32 experts)
    const int tok0  = blockIdx.x * M_TOK;

    if (tid < EE) { bssum[tid] = 0.f; bcnt[tid] = 0.f; }
    if (tid == 0) fl_cnt = 0;

    // A: lane covers rows (lane&15) [mh=0] and +16 [mh=1];
    //    k = kq*512 + ks*32 + (lane>>4)*8 + j  (contiguous 8 floats)
    const float* __restrict__ xp0 =
        x + (size_t)(tok0 + (lane & 15)) * HH + kq * 512 + (lane >> 4) * 8;
    const float* __restrict__ xp1 = xp0 + (size_t)16 * HH;
    // B: shorts at ((nt*64 + kq*16 + ks)*64 + lane)*8 ; this wave's nt = nth*2 + {0,1}
    //    nti stride = 32768 shorts, ks stride = 512 shorts. Disjoint per wave.
    const unsigned short* __restrict__ bhp =
        bhi + ((size_t)((nth * 2) * 64 + kq * 16) * 64 + lane) * 8;
    const unsigned short* __restrict__ blp =
        blo + ((size_t)((nth * 2) * 64 + kq * 16) * 64 + lane) * 8;

    f4v acc00 = {0.f,0.f,0.f,0.f}, acc01 = {0.f,0.f,0.f,0.f};   // [mh][nti]
    f4v acc10 = {0.f,0.f,0.f,0.f}, acc11 = {0.f,0.f,0.f,0.f};

    v4f A[2][4];          // ping-pong: [buf][mh*2 + half]
    s8v BH[2][2], BL[2][2];                     // [buf][nti]

    // prologue: load ks=0 into buf 0
    A[0][0] = *(const v4f*)(xp0);
    A[0][1] = *(const v4f*)(xp0 + 4);
    A[0][2] = *(const v4f*)(xp1);
    A[0][3] = *(const v4f*)(xp1 + 4);
    BH[0][0] = *(const s8v*)(bhp);
    BH[0][1] = *(const s8v*)(bhp + 32768);
    BL[0][0] = *(const s8v*)(blp);
    BL[0][1] = *(const s8v*)(blp + 32768);

#pragma unroll
    for (int ks = 0; ks < 16; ++ks) {
        const int cur = ks & 1, nxt = cur ^ 1;
        if (ks < 15) {                          // issue next-ks loads FIRST
            A[nxt][0] = *(const v4f*)(xp0 + (ks + 1) * 32);
            A[nxt][1] = *(const v4f*)(xp0 + (ks + 1) * 32 + 4);
            A[nxt][2] = *(const v4f*)(xp1 + (ks + 1) * 32);
            A[nxt][3] = *(const v4f*)(xp1 + (ks + 1) * 32 + 4);
            BH[nxt][0] = *(const s8v*)(bhp + (ks + 1) * 512);
            BH[nxt][1] = *(const s8v*)(bhp + 32768 + (ks + 1) * 512);
            BL[nxt][0] = *(const s8v*)(blp + (ks + 1) * 512);
            BL[nxt][1] = *(const s8v*)(blp + 32768 + (ks + 1) * 512);
        }
        // fp32 -> bf16 hi/lo split (3-term MFMA, logit err ~1e-5)
        s8v ah0, al0, ah1, al1;
#pragma unroll
        for (int j = 0; j < 8; ++j) {
            float f0 = (j < 4) ? A[cur][0][j] : A[cur][1][j - 4];
            float f1 = (j < 4) ? A[cur][2][j] : A[cur][3][j - 4];
            unsigned short h0 = f2bf(f0), h1 = f2bf(f1);
            ah0[j] = (short)h0; al0[j] = (short)f2bf(f0 - bf2f(h0));
            ah1[j] = (short)h1; al1[j] = (short)f2bf(f1 - bf2f(h1));
        }
        acc00 = __builtin_amdgcn_mfma_f32_16x16x32_bf16(ah0, BH[cur][0], acc00, 0, 0, 0);
        acc00 = __builtin_amdgcn_mfma_f32_16x16x32_bf16(ah0, BL[cur][0], acc00, 0, 0, 0);
        acc00 = __builtin_amdgcn_mfma_f32_16x16x32_bf16(al0, BH[cur][0], acc00, 0, 0, 0);
        acc01 = __builtin_amdgcn_mfma_f32_16x16x32_bf16(ah0, BH[cur][1], acc01, 0, 0, 0);
        acc01 = __builtin_amdgcn_mfma_f32_16x16x32_bf16(ah0, BL[cur][1], acc01, 0, 0, 0);
        acc01 = __builtin_amdgcn_mfma_f32_16x16x32_bf16(al0, BH[cur][1], acc01, 0, 0, 0);
        acc10 = __builtin_amdgcn_mfma_f32_16x16x32_bf16(ah1, BH[cur][0], acc10, 0, 0, 0);
        acc10 = __builtin_amdgcn_mfma_f32_16x16x32_bf16(ah1, BL[cur][0], acc10, 0, 0, 0);
        acc10 = __builtin_amdgcn_mfma_f32_16x16x32_bf16(al1, BH[cur][0], acc10, 0, 0, 0);
        acc11 = __builtin_amdgcn_mfma_f32_16x16x32_bf16(ah1, BH[cur][1], acc11, 0, 0, 0);
        acc11 = __builtin_amdgcn_mfma_f32_16x16x32_bf16(ah1, BL[cur][1], acc11, 0, 0, 0);
        acc11 = __builtin_amdgcn_mfma_f32_16x16x32_bf16(al1, BH[cur][1], acc11, 0, 0, 0);
    }

    // ---- cross-wave K-reduction -> lg tile ----
    // C-layout per tile: col16 = lane&15, row16 = (lane>>4)*4 + r
    {
        const int r0 = (lane >> 4) * 4;
        const int c0 = nth * 32 + (lane & 15);
        if (kq != 0) {
#pragma unroll
            for (int r = 0; r < 4; ++r) {
                accLDS[kq - 1][r0 + r][c0]           = acc00[r];
                accLDS[kq - 1][r0 + r][c0 + 16]      = acc01[r];
                accLDS[kq - 1][16 + r0 + r][c0]      = acc10[r];
                accLDS[kq - 1][16 + r0 + r][c0 + 16] = acc11[r];
            }
        }
        __syncthreads();
        if (kq == 0) {
#pragma unroll
            for (int r = 0; r < 4; ++r) {
                lg[r0 + r][c0] = acc00[r] + accLDS[0][r0 + r][c0]
                               + accLDS[1][r0 + r][c0] + accLDS[2][r0 + r][c0];
                lg[r0 + r][c0 + 16] = acc01[r] + accLDS[0][r0 + r][c0 + 16]
                               + accLDS[1][r0 + r][c0 + 16] + accLDS[2][r0 + r][c0 + 16];
                lg[16 + r0 + r][c0] = acc10[r] + accLDS[0][16 + r0 + r][c0]
                               + accLDS[1][16 + r0 + r][c0] + accLDS[2][16 + r0 + r][c0];
                lg[16 + r0 + r][c0 + 16] = acc11[r] + accLDS[0][16 + r0 + r][c0 + 16]
                               + accLDS[1][16 + r0 + r][c0 + 16] + accLDS[2][16 + r0 + r][c0 + 16];
            }
        }
        __syncthreads();
    }

    // ---- fused gate: each wave handles 4 tokens, lane = expert ----
    float ssum_l = 0.f;                         // per-expert softmax-score sum (4 tokens)

#pragma unroll
    for (int r = 0; r < 4; ++r) {
        const int tl = wavei * 4 + r;
        const int t  = tok0 + tl;
        float l = lg[tl][lane];

        // softmax score (fp32, feeds aux only)
        float mx = l;
#pragma unroll
        for (int off = 32; off; off >>= 1) mx = fmaxf(mx, __shfl_xor(mx, off, 64));
        float p = __expf(l - mx);
        float Z = p;
#pragma unroll
        for (int off = 32; off; off >>= 1) Z += __shfl_xor(Z, off, 64);
        ssum_l += p / Z;

        // top-3 by fp32 logit (tie -> lower index); cl[2] only feeds the flag
        float v = l;
        int cand[3]; float cl[3];
#pragma unroll
        for (int q = 0; q < 3; ++q) {
            float bv = v; int bi = lane;
#pragma unroll
            for (int off = 32; off; off >>= 1) {
                float ov = __shfl_xor(bv, off, 64);
                int   oi = __shfl_xor(bi, off, 64);
                if (ov > bv || (ov == bv && oi < bi)) { bv = ov; bi = oi; }
            }
            cand[q] = bi; cl[q] = bv;
            if (lane == bi) v = -3.4e38f;
        }

        if (lane == 0) {
            atomicAdd(&bcnt[cand[0]], 1.f);      // LDS atomics, trivial
            atomicAdd(&bcnt[cand[1]], 1.f);
            float w1 = 1.f / (1.f + __expf(cl[1] - cl[0]));  // softmax denom cancels
            out_idx[t * 2]     = (float)cand[0];
            out_idx[t * 2 + 1] = (float)cand[1];
            out_w[t * 2]       = w1;
            out_w[t * 2 + 1]   = 1.f - w1;
            if (cl[0] - cl[1] < TAU || cl[1] - cl[2] < TAU) {
                int pos = atomicAdd(&fl_cnt, 1);
                fl[pos] = tl;
            }
        }
    }

    atomicAdd(&bssum[lane], ssum_l);            // 8 waves -> LDS
    __syncthreads();                            // bcnt/bssum/fl complete

    // ---- publish per-block partials: ONE relaxed atomicAdd per expert ----
    {
        const int b   = tok0 >> 12;             // block-uniform batch index
        const int rep = (blockIdx.x & (NREP - 1)) * (BB * EE);
        if (tid < EE)
            atomicAdd(&g_cnt[rep + b * EE + tid], bcnt[tid]);
        else if (tid < 2 * EE)
            atomicAdd(&g_ssum[rep + b * EE + (tid - EE)], bssum[tid - EE]);
    }

    // ---- inline fp64 exact re-rank of this block's flagged tokens (~1/block) ----
    const int nfl = fl_cnt;
    for (int i = wavei; i < nfl; i += 8) {
        const int tl = fl[i];
        const int t  = tok0 + tl;
        float l = lg[tl][lane];

        float v = l;
        int cand4[4];
#pragma unroll
        for (int q = 0; q < 4; ++q) {
            float bv = v; int bi = lane;
#pragma unroll
            for (int off = 32; off; off >>= 1) {
                float ov = __shfl_xor(bv, off, 64);
                int   oi = __shfl_xor(bi, off, 64);
                if (ov > bv || (ov == bv && oi < bi)) { bv = ov; bi = oi; }
            }
            cand4[q] = bi;
            if (lane == bi) v = -3.4e38f;
        }

        const float* __restrict__ xt  = x + (size_t)t * HH;          // L2-hot
        const float* __restrict__ w0p = w + (size_t)cand4[0] * HH;
        const float* __restrict__ w1p = w + (size_t)cand4[1] * HH;
        const float* __restrict__ w2p = w + (size_t)cand4[2] * HH;
        const float* __restrict__ w3p = w + (size_t)cand4[3] * HH;
        double d0 = 0.0, d1 = 0.0, d2 = 0.0, d3 = 0.0;
#pragma unroll
        for (int ii = 0; ii < 8; ++ii) {
            const int k = ii * 256 + lane * 4;
            v4f xv = *(const v4f*)(xt + k);
            v4f a0 = *(const v4f*)(w0p + k);
            v4f a1 = *(const v4f*)(w1p + k);
            v4f a2 = *(const v4f*)(w2p + k);
            v4f a3 = *(const v4f*)(w3p + k);
            double dx0 = (double)xv.x, dx1 = (double)xv.y;
            double dx2 = (double)xv.z, dx3 = (double)xv.w;
            d0 = fma(dx0, (double)a0.x, d0); d0 = fma(dx1, (double)a0.y, d0);
            d0 = fma(dx2, (double)a0.z, d0); d0 = fma(dx3, (double)a0.w, d0);
            d1 = fma(dx0, (double)a1.x, d1); d1 = fma(dx1, (double)a1.y, d1);
            d1 = fma(dx2, (double)a1.z, d1); d1 = fma(dx3, (double)a1.w, d1);
            d2 = fma(dx0, (double)a2.x, d2); d2 = fma(dx1, (double)a2.y, d2);
            d2 = fma(dx2, (double)a2.z, d2); d2 = fma(dx3, (double)a2.w, d2);
            d3 = fma(dx0, (double)a3.x, d3); d3 = fma(dx1, (double)a3.y, d3);
            d3 = fma(dx2, (double)a3.z, d3); d3 = fma(dx3, (double)a3.w, d3);
        }
#pragma unroll
        for (int off = 32; off; off >>= 1) {
            d0 += __shfl_xor(d0, off, 64);
            d1 += __shfl_xor(d1, off, 64);
            d2 += __shfl_xor(d2, off, 64);
            d3 += __shfl_xor(d3, off, 64);
        }

        double bd[4] = {d0, d1, d2, d3};
        int e1 = cand4[0]; double l1 = bd[0];
#pragma unroll
        for (int q = 1; q < 4; ++q)
            if (bd[q] > l1 || (bd[q] == l1 && cand4[q] < e1)) { l1 = bd[q]; e1 = cand4[q]; }
        int e2 = -1; double l2 = -1e300;
#pragma unroll
        for (int q = 0; q < 4; ++q) {
            if (cand4[q] == e1) continue;
            if (e2 < 0 || bd[q] > l2 || (bd[q] == l2 && cand4[q] < e2)) { l2 = bd[q]; e2 = cand4[q]; }
        }

        double w1d = 1.0 / (1.0 + exp(l2 - l1));
        if (lane == 0) {
            out_idx[t * 2]     = (float)e1;
            out_idx[t * 2 + 1] = (float)e2;
            out_w[t * 2]       = (float)w1d;
            out_w[t * 2 + 1]   = (float)(1.0 - w1d);
        }
    }
}

// aux = 0.01/(B * 128 * S) * sum_{b,e} cnt[b,e]*ssum[b,e]   (E/(S*K)=1/128)
__global__ void finalize(const float* __restrict__ g_cnt,
                         const float* __restrict__ g_ssum,
                         float* __restrict__ aux_out) {
    int lane = threadIdx.x;  // 64 threads, lane = expert
    float a = 0.f;
    for (int b = 0; b < BB; ++b) {
        float c = 0.f, ss = 0.f;
#pragma unroll
        for (int r = 0; r < NREP; ++r) {
            c  += g_cnt[r * (BB * EE) + b * EE + lane];
            ss += g_ssum[r * (BB * EE) + b * EE + lane];
        }
        a += c * ss;
    }
#pragma unroll
    for (int off = 32; off; off >>= 1) a += __shfl_xor(a, off, 64);
    if (lane == 0) aux_out[0] = a * (0.01f / (4.f * 128.f * 4096.f));
}

extern "C" void kernel_launch(void* const* d_in, const int* in_sizes, int n_in,
                              void* d_out, int out_size, void* d_ws, size_t ws_size,
                              hipStream_t stream) {
    const float* x = (const float*)d_in[0];   // [4,4096,2048]
    const float* w = (const float*)d_in[1];   // [64,2048]
    float* out = (float*)d_out;
    float* out_idx = out;                 // [16384*2]
    float* out_w   = out + 2 * TT;        // [16384*2]
    float* aux     = out + 4 * TT;        // [1]

    // ws layout
    unsigned short* bhi = (unsigned short*)d_ws;                    // 256 KB
    unsigned short* blo = bhi + (size_t)EE * HH;                    // 256 KB
    float* g_cnt  = (float*)(blo + (size_t)EE * HH);                // 8 KB
    float* g_ssum = g_cnt + NREP * BB * EE;                         // 8 KB

    prep_b<<<(EE * HH) / 256, 256, 0, stream>>>(w, bhi, blo, g_cnt);
    gemm_gate<<<NBLK, 512, 0, stream>>>(x, bhi, blo, w, out_idx, out_w,
                                        g_cnt, g_ssum);
    finalize<<<1, 64, 0, stream>>>(g_cnt, g_ssum, aux);
}